// Round 5
// baseline (161.632 us; speedup 1.0000x reference)
//
#include <hip/hip_runtime.h>

#define NN 50000
#define NE 600000
#define NR 500
#define DD 128
#define CAP 64   // bucket capacity per node; deg ~ Poisson(12), P(any>64) ~ 1e-25

// 1 cursor per 128B line (r2: cross-XCD per-line atomic serialization fix)
#define CSTRIDE 32

// NOTE (r3 post-mortem): hipLaunchCooperativeKernel is NOT capturable by this
// harness's hipGraph (silent launch failure -> all-zero output).
// NOTE (r4): __builtin_nontemporal_load needs ext_vector pointers, not float4
// (HIP_vector_type struct) -> use f32x4v.

// ---------------------------------------------------------------------------
// Workspace layout (int units):
//   OFF_CUR : NN*CSTRIDE padded cursors (zeroed by hipMemsetAsync)
//   OFF_BKT : NN*CAP packed (src | typ<<16) bucket entries
//   OFF_HB  : h as bf16   (NN*DD)
//   OFF_RELB: rel as bf16 (NR*DD)
//   OFF_BP  : [W;L] bf16 MFMA B-fragments (32768 bf16)
// ---------------------------------------------------------------------------
#define OFF_CUR  0
#define OFF_BKT  (NN * CSTRIDE)
#define OFF_HB   (OFF_BKT + NN * CAP)
#define OFF_RELB (OFF_HB + NN * DD / 2)
#define OFF_BP   (OFF_RELB + NR * DD / 2)

typedef __bf16 bf16x8 __attribute__((ext_vector_type(8)));
typedef float  f32x4  __attribute__((ext_vector_type(4)));
typedef float  f32x4v __attribute__((ext_vector_type(4)));

// Merged grid: fill blocks FIRST (long pole: atomic-latency-bound, starts
// immediately), then the BW-bound conversion blocks stream in underneath.
#define FILL_BLOCKS ((NE + 255) / 256)   // 2344
#define HB_BLOCKS   3125   // 50000*128/8/256
#define RELB_BLOCKS 32     // 500*128/8 = 8000 threads
#define PB_BLOCKS   128    // 32768 threads
#define PREP_BLOCKS (FILL_BLOCKS + HB_BLOCKS + RELB_BLOCKS + PB_BLOCKS)

// ---------------------------------------------------------------------------
// prep_fill: (fill) bucket scatter via padded cursor atomics, 1 edge/thread;
//            (a) h->bf16, (b) rel->bf16, (c) pack [W;L] into MFMA B frags:
//   n = ntile*16 + (lane&15), k = kstep*32 + (lane>>4)*8 + j
//   Bp[((kstep*8 + ntile)*64 + lane)*8 + j] = bf16(B[k][n])
// Single-use streams (h fp32, edge arrays) use nontemporal loads so the
// h_bf/bucket WRITES keep L2 residency for the fused kernel.
// ---------------------------------------------------------------------------
__global__ __launch_bounds__(256) void prep_fill(
    const float* __restrict__ h, const float* __restrict__ rel,
    const float* __restrict__ W, const float* __restrict__ L,
    __bf16* __restrict__ h_bf, __bf16* __restrict__ rel_bf,
    __bf16* __restrict__ Bp,
    const int* __restrict__ esrc, const int* __restrict__ edst,
    const int* __restrict__ etyp, int* __restrict__ cursor,
    unsigned* __restrict__ bucket)
{
    int b = blockIdx.x;
    if (b < FILL_BLOCKS) {
        int e = b * 256 + threadIdx.x;
        if (e >= NE) return;
        int s = __builtin_nontemporal_load(esrc + e);
        int d = __builtin_nontemporal_load(edst + e);
        int t = __builtin_nontemporal_load(etyp + e);
        int pos = atomicAdd(&cursor[(size_t)d * CSTRIDE], 1);
        if (pos < CAP) bucket[(size_t)d * CAP + pos] = (unsigned)s | ((unsigned)t << 16);
        return;
    }
    b -= FILL_BLOCKS;
    if (b < HB_BLOCKS) {
        int t = b * 256 + threadIdx.x;            // 8 floats per thread
        const f32x4v* src = (const f32x4v*)h + (size_t)t * 2;
        f32x4v v0 = __builtin_nontemporal_load(src);
        f32x4v v1 = __builtin_nontemporal_load(src + 1);
        bf16x8 o;
        o[0]=(__bf16)v0[0]; o[1]=(__bf16)v0[1]; o[2]=(__bf16)v0[2]; o[3]=(__bf16)v0[3];
        o[4]=(__bf16)v1[0]; o[5]=(__bf16)v1[1]; o[6]=(__bf16)v1[2]; o[7]=(__bf16)v1[3];
        *(bf16x8*)(h_bf + (size_t)t * 8) = o;
    } else if (b < HB_BLOCKS + RELB_BLOCKS) {
        int t = (b - HB_BLOCKS) * 256 + threadIdx.x;
        if (t < NR * DD / 8) {
            const f32x4v* src = (const f32x4v*)rel + (size_t)t * 2;
            f32x4v v0 = src[0], v1 = src[1];
            bf16x8 o;
            o[0]=(__bf16)v0[0]; o[1]=(__bf16)v0[1]; o[2]=(__bf16)v0[2]; o[3]=(__bf16)v0[3];
            o[4]=(__bf16)v1[0]; o[5]=(__bf16)v1[1]; o[6]=(__bf16)v1[2]; o[7]=(__bf16)v1[3];
            *(bf16x8*)(rel_bf + (size_t)t * 8) = o;
        }
    } else {
        int t = (b - HB_BLOCKS - RELB_BLOCKS) * 256 + threadIdx.x;  // [0,32768)
        int lane  = (t >> 3) & 63;
        int ntile = (t >> 9) & 7;
        int kstep = t >> 12;
        int n = ntile * 16 + (lane & 15);
        int k = kstep * 32 + (lane >> 4) * 8 + (t & 7);
        float v = (k < DD) ? W[k * DD + n] : L[(k - DD) * DD + n];
        Bp[t] = (__bf16)v;
    }
}

// ---------------------------------------------------------------------------
// fused_gather_mfma: 16 nodes per block (grid = NN/16 = 3125, exact).
//   phase 1: gather (16 lanes/node, bf16x8/lane, fp32 acc, *norm -> bf16 LDS)
//            8-edge batches; NEXT batch's bucket words prefetched during the
//            current batch (removes the bk->addr->load serial chain: one L2
//            latency per batch off the critical path). Over-read of <=8 slots
//            past n stays inside the allocated bucket/workspace region.
//   phase 2: all 4 waves share the 16 A-rows; wave w computes n-tiles
//            {2w, 2w+1}: 8 ksteps x 2 = 16 MFMA/wave. relu, nontemporal store.
// ---------------------------------------------------------------------------
#define AP 264   // bf16 pitch; row = 528 B

__global__ __launch_bounds__(256) void fused_gather_mfma(
    const __bf16* __restrict__ h_bf, const __bf16* __restrict__ rel_bf,
    const float* __restrict__ norm, const int* __restrict__ cursor,
    const unsigned* __restrict__ bucket, const __bf16* __restrict__ Bp,
    float* __restrict__ out)
{
    __shared__ __bf16 As[16 * AP];   // 8448 B
    int tid = threadIdx.x;
    int row0 = blockIdx.x * 16;
    int g    = tid >> 4;             // node group 0..15
    int gl   = tid & 15;             // lane within node: bf16 [gl*8, gl*8+8)
    int node = row0 + g;             // always < NN (exact grid)

    // hoisted independent loads: own h row (for k>=128 stage), norm, degree
    bf16x8 own_h = *(const bf16x8*)(h_bf + (size_t)node * DD + gl * 8);
    float sc = norm[node];
    int n = cursor[(size_t)node * CSTRIDE];
    n = (n < CAP) ? n : CAP;
    const unsigned* bk = bucket + (size_t)node * CAP;

    float acc[8];
#pragma unroll
    for (int j = 0; j < 8; ++j) acc[j] = 0.f;

    int i = 0;
    if (n >= 8) {
        unsigned w[8];
#pragma unroll
        for (int u = 0; u < 8; ++u) w[u] = bk[u];
        for (; i + 7 < n; i += 8) {
            bf16x8 a[8], r[8];
#pragma unroll
            for (int u = 0; u < 8; ++u) {
                a[u] = *(const bf16x8*)(h_bf   + (size_t)(w[u] & 0xFFFFu) * DD + gl * 8);
                r[u] = *(const bf16x8*)(rel_bf + (size_t)(w[u] >> 16)     * DD + gl * 8);
            }
            unsigned wn[8];   // prefetch next batch's words (over-read safe)
#pragma unroll
            for (int u = 0; u < 8; ++u) wn[u] = bk[i + 8 + u];
#pragma unroll
            for (int u = 0; u < 8; ++u)
#pragma unroll
                for (int j = 0; j < 8; ++j)
                    acc[j] += (float)a[u][j] + (float)r[u][j];
#pragma unroll
            for (int u = 0; u < 8; ++u) w[u] = wn[u];
        }
    }
    for (; i + 1 < n; i += 2) {
        unsigned p0 = bk[i], p1 = bk[i + 1];
        bf16x8 a0 = *(const bf16x8*)(h_bf   + (size_t)(p0 & 0xFFFFu) * DD + gl * 8);
        bf16x8 b0 = *(const bf16x8*)(rel_bf + (size_t)(p0 >> 16)     * DD + gl * 8);
        bf16x8 a1 = *(const bf16x8*)(h_bf   + (size_t)(p1 & 0xFFFFu) * DD + gl * 8);
        bf16x8 b1 = *(const bf16x8*)(rel_bf + (size_t)(p1 >> 16)     * DD + gl * 8);
#pragma unroll
        for (int j = 0; j < 8; ++j)
            acc[j] += ((float)a0[j] + (float)b0[j]) + ((float)a1[j] + (float)b1[j]);
    }
    if (i < n) {
        unsigned p0 = bk[i];
        bf16x8 a0 = *(const bf16x8*)(h_bf   + (size_t)(p0 & 0xFFFFu) * DD + gl * 8);
        bf16x8 b0 = *(const bf16x8*)(rel_bf + (size_t)(p0 >> 16)     * DD + gl * 8);
#pragma unroll
        for (int j = 0; j < 8; ++j) acc[j] += (float)a0[j] + (float)b0[j];
    }

    bf16x8 o;
#pragma unroll
    for (int j = 0; j < 8; ++j) o[j] = (__bf16)(acc[j] * sc);
    *(bf16x8*)&As[g * AP + gl * 8] = o;
    *(bf16x8*)&As[g * AP + DD + gl * 8] = own_h;
    __syncthreads();

    // ---- phase 2: MFMA. wave w -> n-tiles 2w, 2w+1 over shared 16 A-rows.
    int lane = tid & 63;
    int wave = tid >> 6;
    int aoff = (lane & 15) * AP + (lane >> 4) * 8;

    f32x4 c0 = (f32x4)0.f, c1 = (f32x4)0.f;
    int nt0 = wave * 2;
#pragma unroll
    for (int kstep = 0; kstep < 8; ++kstep) {
        bf16x8 a = *(const bf16x8*)&As[aoff + kstep * 32];
        const __bf16* bbase = Bp + ((size_t)(kstep * 8 + nt0) * 64 + lane) * 8;
        bf16x8 b0 = *(const bf16x8*)bbase;
        bf16x8 b1 = *(const bf16x8*)(bbase + 64 * 8);
        c0 = __builtin_amdgcn_mfma_f32_16x16x32_bf16(a, b0, c0, 0, 0, 0);
        c1 = __builtin_amdgcn_mfma_f32_16x16x32_bf16(a, b1, c1, 0, 0, 0);
    }

    // epilogue: C/D layout col=lane&15, row=(lane>>4)*4+reg; rows all < NN.
    // nontemporal: out is a 25.6MB single-use stream; don't evict h_bf from L2
    int quad = lane >> 4;
    int col  = lane & 15;
#pragma unroll
    for (int reg = 0; reg < 4; ++reg) {
        float* op = out + (size_t)(row0 + quad * 4 + reg) * DD + col;
        __builtin_nontemporal_store(fmaxf(c0[reg], 0.f), op + nt0 * 16);
        __builtin_nontemporal_store(fmaxf(c1[reg], 0.f), op + (nt0 + 1) * 16);
    }
}

extern "C" void kernel_launch(void* const* d_in, const int* in_sizes, int n_in,
                              void* d_out, int out_size, void* d_ws, size_t ws_size,
                              hipStream_t stream) {
    const float* h    = (const float*)d_in[0];
    const float* norm = (const float*)d_in[1];
    const float* rel  = (const float*)d_in[2];
    const float* W    = (const float*)d_in[3];
    const float* L    = (const float*)d_in[4];
    const int* esrc   = (const int*)d_in[5];
    const int* edst   = (const int*)d_in[6];
    const int* etyp   = (const int*)d_in[7];
    float* out = (float*)d_out;

    int* ws = (int*)d_ws;
    int* cursor      = ws + OFF_CUR;
    unsigned* bucket = (unsigned*)(ws + OFF_BKT);
    __bf16* h_bf     = (__bf16*)(ws + OFF_HB);
    __bf16* rel_bf   = (__bf16*)(ws + OFF_RELB);
    __bf16* Bp       = (__bf16*)(ws + OFF_BP);

    // cursor zeroing must precede ALL fill atomics -> stream-ordered memset
    (void)hipMemsetAsync(cursor, 0, (size_t)NN * CSTRIDE * sizeof(int), stream);
    prep_fill<<<PREP_BLOCKS, 256, 0, stream>>>(h, rel, W, L, h_bf, rel_bf, Bp,
                                               esrc, edst, etyp, cursor, bucket);
    fused_gather_mfma<<<NN / 16, 256, 0, stream>>>(h_bf, rel_bf, norm, cursor,
                                                   bucket, Bp, out);
}

// Round 6
// 157.260 us; speedup vs baseline: 1.0278x; 1.0278x over previous
//
#include <hip/hip_runtime.h>

#define NN 50000
#define NE 600000
#define NR 500
#define DD 128
#define CAP 64   // bucket capacity per node; deg ~ Poisson(12), P(any>64) ~ 1e-25

// 1 cursor per 128B line (r2: cross-XCD per-line atomic serialization fix)
#define CSTRIDE 32

// NOTE (r3): hipLaunchCooperativeKernel is NOT capturable by this harness's
// hipGraph (silent launch failure -> all-zero output). Multi-dispatch only.
// NOTE (r4): __builtin_nontemporal_load needs ext_vector pointers, not float4.
// NOTE (r6): cursors live in static __device__ BSS (zero-init at module load,
// NOT poisoned by the harness -- only d_ws is). fused resets each cursor to 0
// after reading it, so the "cursors are zero before fill" invariant holds for
// every fill->fused sequence. Saves the hipMemsetAsync dispatch.
__device__ int g_cursor[NN * CSTRIDE];   // 6.4 MB BSS

// Zero rows: gather batches are padded to 8 with a sentinel word pointing at
// an all-zero h_bf row (index NN) and all-zero rel_bf row (index NR) ->
// padded slots contribute exactly +0.0, stay L1-hot, no masking VALU.
#define ZW ((unsigned)NN | ((unsigned)NR << 16))

// ---------------------------------------------------------------------------
// Workspace layout (int units):
//   OFF_BKT : NN*CAP packed (src | typ<<16) bucket entries
//   OFF_HB  : h as bf16   ((NN+1)*DD, last row = zeros)
//   OFF_RELB: rel as bf16 ((NR+1)*DD, last row = zeros)
//   OFF_BP  : [W;L] bf16 MFMA B-fragments (32768 bf16)
// ---------------------------------------------------------------------------
#define OFF_BKT  0
#define OFF_HB   (OFF_BKT + NN * CAP)
#define OFF_RELB (OFF_HB + (NN + 1) * DD / 2)
#define OFF_BP   (OFF_RELB + (NR + 1) * DD / 2)

typedef __bf16 bf16x8 __attribute__((ext_vector_type(8)));
typedef float  f32x4  __attribute__((ext_vector_type(4)));
typedef float  f32x4v __attribute__((ext_vector_type(4)));

// Merged grid: fill blocks FIRST (long pole: atomic-latency-bound, starts
// immediately), then the BW-bound conversion blocks stream in underneath.
#define FILL_BLOCKS ((NE + 255) / 256)   // 2344
#define HB_BLOCKS   3125   // 50000*128/8/256
#define RELB_BLOCKS 32     // 500*128/8 = 8000 conv threads + 32 zero-row threads
#define PB_BLOCKS   128    // 32768 threads
#define PREP_BLOCKS (FILL_BLOCKS + HB_BLOCKS + RELB_BLOCKS + PB_BLOCKS)

// ---------------------------------------------------------------------------
// prep_fill: (fill) bucket scatter via padded cursor atomics, 1 edge/thread;
//            (a) h->bf16, (b) rel->bf16 (+ zero rows), (c) pack [W;L] into
//            MFMA B frags:
//   n = ntile*16 + (lane&15), k = kstep*32 + (lane>>4)*8 + j
//   Bp[((kstep*8 + ntile)*64 + lane)*8 + j] = bf16(B[k][n])
// ---------------------------------------------------------------------------
__global__ __launch_bounds__(256) void prep_fill(
    const float* __restrict__ h, const float* __restrict__ rel,
    const float* __restrict__ W, const float* __restrict__ L,
    __bf16* __restrict__ h_bf, __bf16* __restrict__ rel_bf,
    __bf16* __restrict__ Bp,
    const int* __restrict__ esrc, const int* __restrict__ edst,
    const int* __restrict__ etyp, unsigned* __restrict__ bucket)
{
    int b = blockIdx.x;
    if (b < FILL_BLOCKS) {
        int e = b * 256 + threadIdx.x;
        if (e >= NE) return;
        int s = __builtin_nontemporal_load(esrc + e);
        int d = __builtin_nontemporal_load(edst + e);
        int t = __builtin_nontemporal_load(etyp + e);
        int pos = atomicAdd(&g_cursor[(size_t)d * CSTRIDE], 1);
        if (pos < CAP) bucket[(size_t)d * CAP + pos] = (unsigned)s | ((unsigned)t << 16);
        return;
    }
    b -= FILL_BLOCKS;
    if (b < HB_BLOCKS) {
        int t = b * 256 + threadIdx.x;            // 8 floats per thread
        const f32x4v* src = (const f32x4v*)h + (size_t)t * 2;
        f32x4v v0 = __builtin_nontemporal_load(src);
        f32x4v v1 = __builtin_nontemporal_load(src + 1);
        bf16x8 o;
        o[0]=(__bf16)v0[0]; o[1]=(__bf16)v0[1]; o[2]=(__bf16)v0[2]; o[3]=(__bf16)v0[3];
        o[4]=(__bf16)v1[0]; o[5]=(__bf16)v1[1]; o[6]=(__bf16)v1[2]; o[7]=(__bf16)v1[3];
        *(bf16x8*)(h_bf + (size_t)t * 8) = o;
    } else if (b < HB_BLOCKS + RELB_BLOCKS) {
        int t = (b - HB_BLOCKS) * 256 + threadIdx.x;
        if (t < NR * DD / 8) {
            const f32x4v* src = (const f32x4v*)rel + (size_t)t * 2;
            f32x4v v0 = src[0], v1 = src[1];
            bf16x8 o;
            o[0]=(__bf16)v0[0]; o[1]=(__bf16)v0[1]; o[2]=(__bf16)v0[2]; o[3]=(__bf16)v0[3];
            o[4]=(__bf16)v1[0]; o[5]=(__bf16)v1[1]; o[6]=(__bf16)v1[2]; o[7]=(__bf16)v1[3];
            *(bf16x8*)(rel_bf + (size_t)t * 8) = o;
        } else if (t < NR * DD / 8 + 16) {         // h_bf zero row (index NN)
            int j = t - NR * DD / 8;
            bf16x8 z;
#pragma unroll
            for (int k = 0; k < 8; ++k) z[k] = (__bf16)0.f;
            *(bf16x8*)(h_bf + (size_t)NN * DD + j * 8) = z;
        } else if (t < NR * DD / 8 + 32) {         // rel_bf zero row (index NR)
            int j = t - NR * DD / 8 - 16;
            bf16x8 z;
#pragma unroll
            for (int k = 0; k < 8; ++k) z[k] = (__bf16)0.f;
            *(bf16x8*)(rel_bf + (size_t)NR * DD + j * 8) = z;
        }
    } else {
        int t = (b - HB_BLOCKS - RELB_BLOCKS) * 256 + threadIdx.x;  // [0,32768)
        int lane  = (t >> 3) & 63;
        int ntile = (t >> 9) & 7;
        int kstep = t >> 12;
        int n = ntile * 16 + (lane & 15);
        int k = kstep * 32 + (lane >> 4) * 8 + (t & 7);
        float v = (k < DD) ? W[k * DD + n] : L[(k - DD) * DD + n];
        Bp[t] = (__bf16)v;
    }
}

// ---------------------------------------------------------------------------
// fused_gather_mfma: 16 nodes per block (grid = NN/16 = 3125, exact).
//   phase 1: gather. Per-node critical chain minimized:
//     - bk[0..8) loaded UNCONDITIONALLY before the cursor value arrives
//       (independent; every bucket has CAP slots)
//     - ONE uniform batch loop, nb=ceil(n/8): invalid slots redirected via
//       cndmask to the zero rows (contribute +0.0, L1-hot) -- no serial tail
//     - next batch's words prefetched during current batch (OOB reads land in
//       the adjacent bucket/h_bf region: in-bounds garbage, discarded)
//     - cursor reset to 0 after read (restores fill invariant, kills memset)
//   phase 2: all 4 waves share the 16 A-rows; wave w computes n-tiles
//            {2w, 2w+1}: 8 ksteps x 2 = 16 MFMA/wave. relu, nontemporal store.
// ---------------------------------------------------------------------------
#define AP 264   // bf16 pitch; row = 528 B (16B-aligned for b128)

__global__ __launch_bounds__(256) void fused_gather_mfma(
    const __bf16* __restrict__ h_bf, const __bf16* __restrict__ rel_bf,
    const float* __restrict__ norm,
    const unsigned* __restrict__ bucket, const __bf16* __restrict__ Bp,
    float* __restrict__ out)
{
    __shared__ __bf16 As[16 * AP];   // 8448 B
    int tid = threadIdx.x;
    int row0 = blockIdx.x * 16;
    int g    = tid >> 4;             // node group 0..15
    int gl   = tid & 15;             // lane within node: bf16 [gl*8, gl*8+8)
    int node = row0 + g;             // always < NN (exact grid)

    // earliest possible: bucket words (independent of cursor value)
    const unsigned* bk = bucket + (size_t)node * CAP;
    unsigned w[8];
#pragma unroll
    for (int u = 0; u < 8; ++u) w[u] = bk[u];

    int n = g_cursor[(size_t)node * CSTRIDE];
    if (gl == 0) g_cursor[(size_t)node * CSTRIDE] = 0;   // restore invariant
    bf16x8 own_h = *(const bf16x8*)(h_bf + (size_t)node * DD + gl * 8);
    float sc = norm[node];
    n = (n < CAP) ? n : CAP;

    float acc[8];
#pragma unroll
    for (int j = 0; j < 8; ++j) acc[j] = 0.f;

    int nb = (n + 7) >> 3;
    for (int b = 0; b < nb; ++b) {
        int rem = n - b * 8;         // >= 1 in any executed batch
        bf16x8 a[8], r[8];
#pragma unroll
        for (int u = 0; u < 8; ++u) {
            unsigned wu = (u < rem) ? w[u] : ZW;   // pad with zero-row word
            a[u] = *(const bf16x8*)(h_bf   + (size_t)(wu & 0xFFFFu) * DD + gl * 8);
            r[u] = *(const bf16x8*)(rel_bf + (size_t)(wu >> 16)     * DD + gl * 8);
        }
#pragma unroll
        for (int u = 0; u < 8; ++u) w[u] = bk[(b + 1) * 8 + u];  // prefetch
#pragma unroll
        for (int u = 0; u < 8; ++u)
#pragma unroll
            for (int j = 0; j < 8; ++j)
                acc[j] += (float)a[u][j] + (float)r[u][j];
    }

    bf16x8 o;
#pragma unroll
    for (int j = 0; j < 8; ++j) o[j] = (__bf16)(acc[j] * sc);
    *(bf16x8*)&As[g * AP + gl * 8] = o;
    *(bf16x8*)&As[g * AP + DD + gl * 8] = own_h;
    __syncthreads();

    // ---- phase 2: MFMA. wave w -> n-tiles 2w, 2w+1 over shared 16 A-rows.
    int lane = tid & 63;
    int wave = tid >> 6;
    int aoff = (lane & 15) * AP + (lane >> 4) * 8;

    f32x4 c0 = (f32x4)0.f, c1 = (f32x4)0.f;
    int nt0 = wave * 2;
#pragma unroll
    for (int kstep = 0; kstep < 8; ++kstep) {
        bf16x8 a = *(const bf16x8*)&As[aoff + kstep * 32];
        const __bf16* bbase = Bp + ((size_t)(kstep * 8 + nt0) * 64 + lane) * 8;
        bf16x8 b0 = *(const bf16x8*)bbase;
        bf16x8 b1 = *(const bf16x8*)(bbase + 64 * 8);
        c0 = __builtin_amdgcn_mfma_f32_16x16x32_bf16(a, b0, c0, 0, 0, 0);
        c1 = __builtin_amdgcn_mfma_f32_16x16x32_bf16(a, b1, c1, 0, 0, 0);
    }

    // epilogue: C/D layout col=lane&15, row=(lane>>4)*4+reg; rows all < NN.
    // nontemporal: out is a 25.6MB single-use stream; don't evict h_bf from L2
    int quad = lane >> 4;
    int col  = lane & 15;
#pragma unroll
    for (int reg = 0; reg < 4; ++reg) {
        float* op = out + (size_t)(row0 + quad * 4 + reg) * DD + col;
        __builtin_nontemporal_store(fmaxf(c0[reg], 0.f), op + nt0 * 16);
        __builtin_nontemporal_store(fmaxf(c1[reg], 0.f), op + (nt0 + 1) * 16);
    }
}

extern "C" void kernel_launch(void* const* d_in, const int* in_sizes, int n_in,
                              void* d_out, int out_size, void* d_ws, size_t ws_size,
                              hipStream_t stream) {
    const float* h    = (const float*)d_in[0];
    const float* norm = (const float*)d_in[1];
    const float* rel  = (const float*)d_in[2];
    const float* W    = (const float*)d_in[3];
    const float* L    = (const float*)d_in[4];
    const int* esrc   = (const int*)d_in[5];
    const int* edst   = (const int*)d_in[6];
    const int* etyp   = (const int*)d_in[7];
    float* out = (float*)d_out;

    int* ws = (int*)d_ws;
    unsigned* bucket = (unsigned*)(ws + OFF_BKT);
    __bf16* h_bf     = (__bf16*)(ws + OFF_HB);
    __bf16* rel_bf   = (__bf16*)(ws + OFF_RELB);
    __bf16* Bp       = (__bf16*)(ws + OFF_BP);

    prep_fill<<<PREP_BLOCKS, 256, 0, stream>>>(h, rel, W, L, h_bf, rel_bf, Bp,
                                               esrc, edst, etyp, bucket);
    fused_gather_mfma<<<NN / 16, 256, 0, stream>>>(h_bf, rel_bf, norm,
                                                   bucket, Bp, out);
}